// Round 9
// baseline (344.349 us; speedup 1.0000x reference)
//
#include <hip/hip_runtime.h>
#include <hip/hip_bf16.h>

#define BB 2
#define NN 2048
#define KVN 2048
#define CC 1024
#define HH 16
#define HD 64

typedef __bf16 bf16;
typedef __attribute__((ext_vector_type(4))) __bf16 bf16x4;
typedef __attribute__((ext_vector_type(8))) __bf16 bf16x8;
typedef __attribute__((ext_vector_type(4))) float f32x4;

__device__ __forceinline__ void gload_lds16(const void* g, void* l) {
  __builtin_amdgcn_global_load_lds(
      (const __attribute__((address_space(1))) void*)g,
      (__attribute__((address_space(3))) void*)l, 16, 0, 0);
}

// ---------------- batched weight transpose: Wt[z][c][r] = (bf16)W_z[r][c]
__global__ __launch_bounds__(256)
void wtrans(const float* __restrict__ qW, const float* __restrict__ kW,
            const float* __restrict__ vW, const float* __restrict__ pW,
            bf16* __restrict__ Wt) {
  __shared__ bf16 t[64][72];
  const float* in = (blockIdx.z == 0) ? qW : (blockIdx.z == 1) ? kW
                    : (blockIdx.z == 2) ? vW : pW;
  bf16* out = Wt + (size_t)blockIdx.z * CC * CC;
  int r0 = blockIdx.y * 64, c0 = blockIdx.x * 64;
  int tid = threadIdx.x;
  int lr = tid >> 3, lc = (tid & 7) * 8;
  for (int p = 0; p < 2; ++p) {
    int rr = lr + p * 32;
    const float* src = &in[(size_t)(r0 + rr) * CC + c0 + lc];
    float4 a = *(const float4*)src;
    float4 b = *(const float4*)(src + 4);
    t[lc + 0][rr] = (bf16)a.x; t[lc + 1][rr] = (bf16)a.y;
    t[lc + 2][rr] = (bf16)a.z; t[lc + 3][rr] = (bf16)a.w;
    t[lc + 4][rr] = (bf16)b.x; t[lc + 5][rr] = (bf16)b.y;
    t[lc + 6][rr] = (bf16)b.z; t[lc + 7][rr] = (bf16)b.w;
  }
  __syncthreads();
  for (int p = 0; p < 2; ++p) {
    int rr = lr + p * 32;
    *(bf16x8*)&out[(size_t)(c0 + rr) * CC + r0 + lc] = *(const bf16x8*)&t[rr][lc];
  }
}

// ---------------- qkv fp32 -> bf16 prepass: Abf[z][row][col], 36 MB HBM (~6us)
__global__ __launch_bounds__(256)
void cvt_qkv(const float* __restrict__ qin, const float* __restrict__ kin,
             const float* __restrict__ vin, bf16* __restrict__ Abf) {
  const int z = blockIdx.y;
  const float* s = (z == 0) ? qin : (z == 1) ? kin : vin;
  size_t off = ((size_t)blockIdx.x * 256 + threadIdx.x) * 8;  // < 4194304
  float4 a = *(const float4*)(s + off);
  float4 b = *(const float4*)(s + off + 4);
  bf16x8 t;
  t[0] = (bf16)a.x; t[1] = (bf16)a.y; t[2] = (bf16)a.z; t[3] = (bf16)a.w;
  t[4] = (bf16)b.x; t[5] = (bf16)b.y; t[6] = (bf16)b.z; t[7] = (bf16)b.w;
  *(bf16x8*)&Abf[(size_t)z * ((size_t)BB * NN * CC) + off] = t;
}

// ---------------- merged QKV GEMM: 128x128 tile, BK=64 (round-8 v8, kept).
// A pre-converted bf16 -> both operands on the proven gload_lds 8-slot path.
// z==0 scale folds log2(e): attn3 then uses exp2 (1 VALU op) for softmax.
__global__ __launch_bounds__(256, 3)
void gemm_qkv(const bf16* __restrict__ Abf, const bf16* __restrict__ Wt,
              const float* __restrict__ pos, bf16* __restrict__ Qp,
              bf16* __restrict__ Kp, bf16* __restrict__ Vp) {
  __shared__ bf16 As[128 * 64];   // 16 KB, chunks of 8: L = r*8 + (c^(r&7))
  __shared__ bf16 Bs[128 * 64];   // 16 KB, same swizzle
  const int bid = blockIdx.x;
  const int u = bid & 7, s = bid >> 3;       // s in [0,96)
  const int nblk = s >> 2;                   // 0..23
  const int m0 = (u * 4 + (s & 3)) * 128;
  const int z = nblk >> 3;
  const int n0 = (nblk & 7) * 128;
  const bf16* A = Abf + (size_t)z * ((size_t)BB * NN * CC);
  const bf16* Bt = Wt + (size_t)z * CC * CC;
  bf16* Out = (z == 0) ? Qp : (z == 1) ? Kp : Vp;
  const int tid = threadIdx.x;
  const int wave = tid >> 6, lane = tid & 63;
  const int quad = lane >> 4, l15 = lane & 15;
  const int waveM = (wave >> 1) * 64, waveN = (wave & 1) * 64;
  f32x4 acc[4][4] = {};

  for (int k0 = 0; k0 < CC; k0 += 64) {
#pragma unroll
    for (int p = 0; p < 4; ++p) {   // B: 1024 bf16-chunks, async direct-to-LDS
      int ch = p * 256 + tid;
      int r = ch >> 3, c = (ch & 7) ^ (r & 7);
      gload_lds16(Bt + (size_t)(n0 + r) * CC + k0 + c * 8, &Bs[ch * 8]);
    }
#pragma unroll
    for (int p = 0; p < 4; ++p) {   // A: same proven path, bf16
      int ch = p * 256 + tid;
      int r = ch >> 3, c = (ch & 7) ^ (r & 7);
      gload_lds16(A + (size_t)(m0 + r) * CC + k0 + c * 8, &As[ch * 8]);
    }
    __syncthreads();
    bf16x8 af[4][2], bfr[4][2];
#pragma unroll
    for (int i = 0; i < 4; ++i) {
      int rA = waveM + i * 16 + l15;
      af[i][0] = *(const bf16x8*)&As[(rA * 8 + (quad ^ (rA & 7))) * 8];
      af[i][1] = *(const bf16x8*)&As[(rA * 8 + ((quad + 4) ^ (rA & 7))) * 8];
      int rB = waveN + i * 16 + l15;
      bfr[i][0] = *(const bf16x8*)&Bs[(rB * 8 + (quad ^ (rB & 7))) * 8];
      bfr[i][1] = *(const bf16x8*)&Bs[(rB * 8 + ((quad + 4) ^ (rB & 7))) * 8];
    }
#pragma unroll
    for (int mi = 0; mi < 4; ++mi)
#pragma unroll
      for (int ni = 0; ni < 4; ++ni) {
        acc[mi][ni] = __builtin_amdgcn_mfma_f32_16x16x32_bf16(
            af[mi][0], bfr[ni][0], acc[mi][ni], 0, 0, 0);
        acc[mi][ni] = __builtin_amdgcn_mfma_f32_16x16x32_bf16(
            af[mi][1], bfr[ni][1], acc[mi][ni], 0, 0, 0);
      }
    __syncthreads();
  }
  // epilogue: C/D col=lane&15, row=quad*4+reg; RoPE in-register for z<2.
  // z==0: scale = hd^-0.5 * log2(e) so attn3's softmax runs in base 2.
  const float scale = (z == 0) ? 0.125f * 1.44269504f : 1.0f;
#pragma unroll
  for (int mi = 0; mi < 4; ++mi) {
#pragma unroll
    for (int r = 0; r < 4; ++r) {
      int m = m0 + waveM + mi * 16 + quad * 4 + r;
      int l = m & (NN - 1);
      if (z == 2) {
#pragma unroll
        for (int ni = 0; ni < 4; ++ni)
          Out[(size_t)m * CC + n0 + waveN + ni * 16 + l15] = (bf16)acc[mi][ni][r];
      } else {
#pragma unroll
        for (int ni = 0; ni < 2; ++ni) {
          int col = n0 + waveN + ni * 16 + l15;
          int d = ni * 16 + l15;                 // head-local, in [0,32)
          float x1 = acc[mi][ni][r], x2 = acc[mi][ni + 2][r];
          float s1, c1, s2f, c2f;
          __sincosf(pos[l * HD + d], &s1, &c1);
          __sincosf(pos[l * HD + d + 32], &s2f, &c2f);
          Out[(size_t)m * CC + col]      = (bf16)((x1 * c1 - x2 * s1) * scale);
          Out[(size_t)m * CC + col + 32] = (bf16)((x2 * c2f + x1 * s2f) * scale);
        }
      }
    }
  }
}

// ---------------- K pack: MFMA-A-frag order. frag (ni,hf): elem[lane][j] =
// K[key=tile*64+ni*16+l15][d=hf*32+quad*8+j]   (A[m=l15][k=quad*8+j] layout)
__global__ __launch_bounds__(256)
void kpack_kernel(const bf16* __restrict__ Kp, bf16* __restrict__ Kpack) {
  int tix = blockIdx.x, h = blockIdx.y, b = blockIdx.z;
  int bh = b * HH + h;
#pragma unroll
  for (int p = 0; p < 2; ++p) {
    int sp = p * 256 + threadIdx.x;
    int fs = sp >> 6, lane = sp & 63, quad = (sp >> 4) & 3, l15 = sp & 15;
    int ni = fs >> 1, hf = fs & 1;
    bf16x8 v = *(const bf16x8*)&Kp[((size_t)(b * KVN + tix * 64 + ni * 16 + l15)) * CC
                                   + h * HD + hf * 32 + quad * 8];
    *(bf16x8*)&Kpack[(((size_t)(bh * 32 + tix)) * 8 + fs) * 512 + lane * 8] = v;
  }
}

// ---------------- V pack: V^T in A-frag order, pre-masked, + mask row (d=64).
__global__ __launch_bounds__(256)
void vpack_kernel(const bf16* __restrict__ Vp, const int* __restrict__ mask,
                  bf16* __restrict__ VpA, bf16* __restrict__ VpB) {
  __shared__ bf16 t[64][80];
  int tix = blockIdx.x, h = blockIdx.y, b = blockIdx.z;
  int j0 = tix * 64, bh = b * HH + h;
  const int* maskb = mask + b * KVN;
  int tid = threadIdx.x;
  int lr = tid >> 3, lc = (tid & 7) * 8;
  for (int p = 0; p < 2; ++p) {
    int j = lr + p * 32;
    int mv = maskb[j0 + j];
    bf16x8 v = *(const bf16x8*)&Vp[(size_t)(b * KVN + j0 + j) * CC + h * HD + lc];
#pragma unroll
    for (int uu = 0; uu < 8; ++uu) t[lc + uu][j] = mv ? v[uu] : (bf16)0.f;
  }
  __syncthreads();
  for (int p = 0; p < 3; ++p) {
    int sp = p * 256 + tid;
    if (sp < 640) {
      int fs = sp >> 6, lane = sp & 63, quad = (sp >> 4) & 3, l15 = sp & 15;
      int ni = fs >> 1, hf = fs & 1;
      bf16x8 v;
      if (ni < 4) {
        v = *(const bf16x8*)&t[ni * 16 + l15][hf * 32 + quad * 8];
      } else {
#pragma unroll
        for (int jj = 0; jj < 8; ++jj)
          v[jj] = (l15 == 0) ? (bf16)(float)maskb[j0 + hf * 32 + quad * 8 + jj]
                             : (bf16)0.f;
      }
      bf16* dst = (fs < 6) ? (VpA + (size_t)fs * (1 << 19))
                           : (VpB + (size_t)(fs - 6) * (1 << 19));
      *(bf16x8*)&dst[((size_t)(bh * 32 + tix)) * 512 + lane * 8] = v;
    }
  }
}

// ---------------- attention v4: per-wave streaming, no barriers in loop.
// Round-8 PMC: MfmaUtil 29 / VALUBusy 40 / Occ 16% (2 blocks/CU, exactly the
// grid) / 31% idle. Changes:
//  (1) 4-way KV split (kh=wave, 8 tiles each): grid 512->1024, waves 2048->
//      4096; merge is two-pass (3 slabs x 10KB = 30KB), LDS 48K->38K so 4
//      blocks/CU fit (155648 <= 160K) -> 2x occupancy. Per-iter instruction
//      mix unchanged (same load:MFMA:VALU ratios).
//  (2) base-2 softmax: Q pre-scaled by log2(e) in gemm_qkv; exp2f = bare
//      v_exp_f32, removing the per-element mul (64 VALU ops/iter/wave).
//  launch_bounds(256,3): VGPR cap ~170 (no forced spill); at ~116 VGPR the
//  limit is LDS = 4 blocks/CU.
__global__ __launch_bounds__(256, 3)
void attn3(const bf16* __restrict__ Qp, const bf16* __restrict__ Kpack,
           const bf16* __restrict__ VpA, const bf16* __restrict__ VpB,
           bf16* __restrict__ X) {
  __shared__ char smem[38912];      // [0,8K): per-wave P; [8K,38K): 3 merge slabs
  const int tid = threadIdx.x, wave = tid >> 6, lane = tid & 63;
  const int quad = lane >> 4, l15 = lane & 15;
  const int bid = blockIdx.x;
  const int u = bid & 7, s = bid >> 3;       // s in [0,128)
  const int bh = u * 4 + (s & 3);            // each XCD: 4 bh -> L2-local K/V
  const int qc = s >> 2;                     // 0..31
  const int b = bh >> 4, h = bh & 15;
  const int kh = wave;                       // 0..3: KV quarter
  const int q0 = qc * 64;
  const int sw = 2 * (l15 & 7);

  bf16* P = (bf16*)(smem + wave * 2048);
  float* mrg = (float*)(smem + 8192);

  bf16x8 qa[4][2];
#pragma unroll
  for (int g = 0; g < 4; ++g) {
    const bf16* qrow = Qp + ((size_t)(b * NN) + q0 + g * 16 + l15) * CC + h * HD;
    qa[g][0] = *(const bf16x8*)&qrow[quad * 8];
    qa[g][1] = *(const bf16x8*)&qrow[32 + quad * 8];
  }

  f32x4 Oacc[4][5] = {};
  const bf16* kbase = Kpack + (size_t)bh * 32 * 8 * 512;

  for (int it = 0; it < 8; ++it) {
    int t = kh * 8 + it;
    bf16x8 kb[8], vb[10];
#pragma unroll
    for (int fs = 0; fs < 8; ++fs)
      kb[fs] = *(const bf16x8*)&kbase[((size_t)t * 8 + fs) * 512 + lane * 8];
#pragma unroll
    for (int fs = 0; fs < 10; ++fs) {
      const bf16* vbs = (fs < 6) ? (VpA + (size_t)fs * (1 << 19))
                                 : (VpB + (size_t)(fs - 6) * (1 << 19));
      vb[fs] = *(const bf16x8*)&vbs[((size_t)(bh * 32 + t)) * 512 + lane * 8];
    }
#pragma unroll
    for (int g = 0; g < 4; ++g) {
      f32x4 sg[4];
      __builtin_amdgcn_s_setprio(1);
#pragma unroll
      for (int ni = 0; ni < 4; ++ni) {
        f32x4 zz = {};
        zz = __builtin_amdgcn_mfma_f32_16x16x32_bf16(kb[ni * 2], qa[g][0], zz, 0, 0, 0);
        zz = __builtin_amdgcn_mfma_f32_16x16x32_bf16(kb[ni * 2 + 1], qa[g][1], zz, 0, 0, 0);
        sg[ni] = zz;
      }
      __builtin_amdgcn_s_setprio(0);
#pragma unroll
      for (int ni = 0; ni < 4; ++ni) {
        bf16x4 pk;
#pragma unroll
        for (int r = 0; r < 4; ++r) pk[r] = (bf16)exp2f(sg[ni][r] - 5.7707802f);
        *(bf16x4*)&P[(l15 * 16 + ((ni * 4 + quad) ^ sw)) * 4] = pk;
      }
      bf16x8 pf0 = *(const bf16x8*)&P[(l15 * 16 + ((quad * 2) ^ sw)) * 4];
      bf16x8 pf1 = *(const bf16x8*)&P[(l15 * 16 + ((8 + quad * 2) ^ sw)) * 4];
      __builtin_amdgcn_s_setprio(1);
#pragma unroll
      for (int ni = 0; ni < 5; ++ni) {
        Oacc[g][ni] = __builtin_amdgcn_mfma_f32_16x16x32_bf16(vb[ni * 2], pf0, Oacc[g][ni], 0, 0, 0);
        Oacc[g][ni] = __builtin_amdgcn_mfma_f32_16x16x32_bf16(vb[ni * 2 + 1], pf1, Oacc[g][ni], 0, 0, 0);
      }
      __builtin_amdgcn_s_setprio(0);
    }
  }

  // two-pass merge: waves 1..3 publish 2 g-groups (10KB slabs), wave 0 sums
  // and writes X. sync #2 guards pass-B overwrite against pass-A reads.
#pragma unroll 1
  for (int pass = 0; pass < 2; ++pass) {
    const int gbase = pass * 2;
    if (wave != 0) {
      float* dst = mrg + (wave - 1) * 2560 + lane * 4;
#pragma unroll
      for (int gg = 0; gg < 2; ++gg)
#pragma unroll
        for (int ni = 0; ni < 5; ++ni)
          *(f32x4*)&dst[(gg * 5 + ni) * 256] = Oacc[gbase + gg][ni];
    }
    __syncthreads();
    if (wave == 0) {
#pragma unroll
      for (int w = 0; w < 3; ++w) {
        float* src = mrg + w * 2560 + lane * 4;
#pragma unroll
        for (int gg = 0; gg < 2; ++gg)
#pragma unroll
          for (int ni = 0; ni < 5; ++ni) {
            f32x4 o = *(const f32x4*)&src[(gg * 5 + ni) * 256];
#pragma unroll
            for (int r = 0; r < 4; ++r) Oacc[gbase + gg][ni][r] += o[r];
          }
      }
#pragma unroll
      for (int gg = 0; gg < 2; ++gg) {
        int g = gbase + gg;
        float ls = __shfl(Oacc[g][4][0], l15, 64);
        float rn = 1.0f / ls;
#pragma unroll
        for (int ni = 0; ni < 4; ++ni) {
          bf16x4 ov;
#pragma unroll
          for (int r = 0; r < 4; ++r) ov[r] = (bf16)(Oacc[g][ni][r] * rn);
          *(bf16x4*)&X[((size_t)(b * NN) + q0 + g * 16 + l15) * CC
                       + h * HD + ni * 16 + quad * 4] = ov;
        }
      }
    }
    __syncthreads();
  }
}

// ---------------- projection GEMM: 64x128 tile, BK=64, 8-slot swizzle, grid 512
__global__ __launch_bounds__(256, 4)
void gemm_proj(const bf16* __restrict__ A, const bf16* __restrict__ Bt,
               float* __restrict__ Out) {
  __shared__ bf16 As[64 * 64];    // 8 KB
  __shared__ bf16 Bs[128 * 64];   // 16 KB
  const int bid = blockIdx.x;
  const int u = bid & 7, s = bid >> 3;        // s in [0,64)
  const int m0 = (u * 8 + (s >> 3)) * 64;
  const int n0 = (s & 7) * 128;
  const int tid = threadIdx.x;
  const int wave = tid >> 6, lane = tid & 63;
  const int quad = lane >> 4, l15 = lane & 15;
  const int waveM = (wave >> 1) * 32, waveN = (wave & 1) * 64;
  f32x4 acc[2][4] = {};

  for (int k0 = 0; k0 < CC; k0 += 64) {
#pragma unroll
    for (int p = 0; p < 2; ++p) {
      int ch = p * 256 + tid;
      int r = ch >> 3, c = (ch & 7) ^ (r & 7);
      gload_lds16(A + (size_t)(m0 + r) * CC + k0 + c * 8, &As[ch * 8]);
    }
#pragma unroll
    for (int p = 0; p < 4; ++p) {
      int ch = p * 256 + tid;
      int r = ch >> 3, c = (ch & 7) ^ (r & 7);
      gload_lds16(Bt + (size_t)(n0 + r) * CC + k0 + c * 8, &Bs[ch * 8]);
    }
    __syncthreads();
    bf16x8 af[2][2], bfr[4][2];
#pragma unroll
    for (int i = 0; i < 2; ++i) {
      int rA = waveM + i * 16 + l15;
      af[i][0] = *(const bf16x8*)&As[(rA * 8 + (quad ^ (rA & 7))) * 8];
      af[i][1] = *(const bf16x8*)&As[(rA * 8 + ((quad + 4) ^ (rA & 7))) * 8];
    }
#pragma unroll
    for (int i = 0; i < 4; ++i) {
      int rB = waveN + i * 16 + l15;
      bfr[i][0] = *(const bf16x8*)&Bs[(rB * 8 + (quad ^ (rB & 7))) * 8];
      bfr[i][1] = *(const bf16x8*)&Bs[(rB * 8 + ((quad + 4) ^ (rB & 7))) * 8];
    }
#pragma unroll
    for (int mi = 0; mi < 2; ++mi)
#pragma unroll
      for (int ni = 0; ni < 4; ++ni) {
        acc[mi][ni] = __builtin_amdgcn_mfma_f32_16x16x32_bf16(
            af[mi][0], bfr[ni][0], acc[mi][ni], 0, 0, 0);
        acc[mi][ni] = __builtin_amdgcn_mfma_f32_16x16x32_bf16(
            af[mi][1], bfr[ni][1], acc[mi][ni], 0, 0, 0);
      }
    __syncthreads();
  }
#pragma unroll
  for (int mi = 0; mi < 2; ++mi)
#pragma unroll
    for (int ni = 0; ni < 4; ++ni)
#pragma unroll
      for (int r = 0; r < 4; ++r) {
        int row = m0 + waveM + mi * 16 + quad * 4 + r;
        int col = n0 + waveN + ni * 16 + l15;
        Out[(size_t)row * CC + col] = acc[mi][ni][r];
      }
}

extern "C" void kernel_launch(void* const* d_in, const int* in_sizes, int n_in,
                              void* d_out, int out_size, void* d_ws, size_t ws_size,
                              hipStream_t stream) {
  const float* q    = (const float*)d_in[0];
  const float* k    = (const float*)d_in[1];
  const float* v    = (const float*)d_in[2];
  const int*   mask = (const int*)d_in[3];
  const float* pos  = (const float*)d_in[4];
  const float* qW   = (const float*)d_in[5];
  const float* kW   = (const float*)d_in[6];
  const float* vW   = (const float*)d_in[7];
  const float* pW   = (const float*)d_in[8];
  float* out = (float*)d_out;

  char* w = (char*)d_ws;
  const size_t MB = 1024 * 1024;
  // layout (<=48MB): Wt@0-8; Qp@8-16; Kp@16-24 (dead after kpack -> X aliases);
  // Vp@24-32 (dead after vpack); Abf@32-44 (12MB, dead after gemm_qkv ->
  // Kpack@32-40 and VpB@40-44 overwrite it); VpA@0-6 over dead qWt/kWt/vWt.
  bf16* Wt    = (bf16*)(w);
  bf16* Qp    = (bf16*)(w + 8 * MB);
  bf16* Kp    = (bf16*)(w + 16 * MB);
  bf16* Vp    = (bf16*)(w + 24 * MB);
  bf16* Abf   = (bf16*)(w + 32 * MB);   // 12 MB, live only through gemm_qkv
  bf16* Kpack = (bf16*)(w + 32 * MB);   // 8 MB, written after Abf is dead
  bf16* VpA   = (bf16*)(w);             // 6 MB over dead qWt/kWt/vWt
  bf16* VpB   = (bf16*)(w + 40 * MB);   // 4 MB, written after Abf is dead
  bf16* X     = (bf16*)(w + 16 * MB);   // aliases Kp

  wtrans<<<dim3(16, 16, 4), 256, 0, stream>>>(qW, kW, vW, pW, Wt);
  cvt_qkv<<<dim3(2048, 3), 256, 0, stream>>>(q, k, v, Abf);
  gemm_qkv<<<dim3(768), 256, 0, stream>>>(Abf, Wt, pos, Qp, Kp, Vp);
  kpack_kernel<<<dim3(KVN / 64, HH, BB), 256, 0, stream>>>(Kp, Kpack);
  vpack_kernel<<<dim3(KVN / 64, HH, BB), 256, 0, stream>>>(Vp, mask, VpA, VpB);
  attn3<<<dim3(1024), 256, 0, stream>>>(Qp, Kpack, VpA, VpB, X);
  gemm_proj<<<dim3(512), 256, 0, stream>>>(X, Wt + 3 * (size_t)CC * CC, out);
}

// Round 10
// 317.517 us; speedup vs baseline: 1.0845x; 1.0845x over previous
//
#include <hip/hip_runtime.h>
#include <hip/hip_bf16.h>

#define BB 2
#define NN 2048
#define KVN 2048
#define CC 1024
#define HH 16
#define HD 64

typedef __bf16 bf16;
typedef __attribute__((ext_vector_type(4))) __bf16 bf16x4;
typedef __attribute__((ext_vector_type(8))) __bf16 bf16x8;
typedef __attribute__((ext_vector_type(4))) float f32x4;

__device__ __forceinline__ void gload_lds16(const void* g, void* l) {
  __builtin_amdgcn_global_load_lds(
      (const __attribute__((address_space(1))) void*)g,
      (__attribute__((address_space(3))) void*)l, 16, 0, 0);
}

// ---------------- batched weight transpose: Wt[z][c][r] = (bf16)W_z[r][c]
__global__ __launch_bounds__(256)
void wtrans(const float* __restrict__ qW, const float* __restrict__ kW,
            const float* __restrict__ vW, const float* __restrict__ pW,
            bf16* __restrict__ Wt) {
  __shared__ bf16 t[64][72];
  const float* in = (blockIdx.z == 0) ? qW : (blockIdx.z == 1) ? kW
                    : (blockIdx.z == 2) ? vW : pW;
  bf16* out = Wt + (size_t)blockIdx.z * CC * CC;
  int r0 = blockIdx.y * 64, c0 = blockIdx.x * 64;
  int tid = threadIdx.x;
  int lr = tid >> 3, lc = (tid & 7) * 8;
  for (int p = 0; p < 2; ++p) {
    int rr = lr + p * 32;
    const float* src = &in[(size_t)(r0 + rr) * CC + c0 + lc];
    float4 a = *(const float4*)src;
    float4 b = *(const float4*)(src + 4);
    t[lc + 0][rr] = (bf16)a.x; t[lc + 1][rr] = (bf16)a.y;
    t[lc + 2][rr] = (bf16)a.z; t[lc + 3][rr] = (bf16)a.w;
    t[lc + 4][rr] = (bf16)b.x; t[lc + 5][rr] = (bf16)b.y;
    t[lc + 6][rr] = (bf16)b.z; t[lc + 7][rr] = (bf16)b.w;
  }
  __syncthreads();
  for (int p = 0; p < 2; ++p) {
    int rr = lr + p * 32;
    *(bf16x8*)&out[(size_t)(c0 + rr) * CC + r0 + lc] = *(const bf16x8*)&t[rr][lc];
  }
}

// ---------------- qkv fp32 -> bf16 prepass: Abf[z][row][col], 36 MB HBM (~6us)
__global__ __launch_bounds__(256)
void cvt_qkv(const float* __restrict__ qin, const float* __restrict__ kin,
             const float* __restrict__ vin, bf16* __restrict__ Abf) {
  const int z = blockIdx.y;
  const float* s = (z == 0) ? qin : (z == 1) ? kin : vin;
  size_t off = ((size_t)blockIdx.x * 256 + threadIdx.x) * 8;  // < 4194304
  float4 a = *(const float4*)(s + off);
  float4 b = *(const float4*)(s + off + 4);
  bf16x8 t;
  t[0] = (bf16)a.x; t[1] = (bf16)a.y; t[2] = (bf16)a.z; t[3] = (bf16)a.w;
  t[4] = (bf16)b.x; t[5] = (bf16)b.y; t[6] = (bf16)b.z; t[7] = (bf16)b.w;
  *(bf16x8*)&Abf[(size_t)z * ((size_t)BB * NN * CC) + off] = t;
}

// ---------------- merged QKV GEMM: 128x128 tile, BK=64 (round-8 v8, kept).
// A pre-converted bf16 -> both operands on the proven gload_lds 8-slot path.
// z==0 scale folds log2(e): attn3 then uses exp2 (1 VALU op) for softmax.
__global__ __launch_bounds__(256, 3)
void gemm_qkv(const bf16* __restrict__ Abf, const bf16* __restrict__ Wt,
              const float* __restrict__ pos, bf16* __restrict__ Qp,
              bf16* __restrict__ Kp, bf16* __restrict__ Vp) {
  __shared__ bf16 As[128 * 64];   // 16 KB, chunks of 8: L = r*8 + (c^(r&7))
  __shared__ bf16 Bs[128 * 64];   // 16 KB, same swizzle
  const int bid = blockIdx.x;
  const int u = bid & 7, s = bid >> 3;       // s in [0,96)
  const int nblk = s >> 2;                   // 0..23
  const int m0 = (u * 4 + (s & 3)) * 128;
  const int z = nblk >> 3;
  const int n0 = (nblk & 7) * 128;
  const bf16* A = Abf + (size_t)z * ((size_t)BB * NN * CC);
  const bf16* Bt = Wt + (size_t)z * CC * CC;
  bf16* Out = (z == 0) ? Qp : (z == 1) ? Kp : Vp;
  const int tid = threadIdx.x;
  const int wave = tid >> 6, lane = tid & 63;
  const int quad = lane >> 4, l15 = lane & 15;
  const int waveM = (wave >> 1) * 64, waveN = (wave & 1) * 64;
  f32x4 acc[4][4] = {};

  for (int k0 = 0; k0 < CC; k0 += 64) {
#pragma unroll
    for (int p = 0; p < 4; ++p) {   // B: 1024 bf16-chunks, async direct-to-LDS
      int ch = p * 256 + tid;
      int r = ch >> 3, c = (ch & 7) ^ (r & 7);
      gload_lds16(Bt + (size_t)(n0 + r) * CC + k0 + c * 8, &Bs[ch * 8]);
    }
#pragma unroll
    for (int p = 0; p < 4; ++p) {   // A: same proven path, bf16
      int ch = p * 256 + tid;
      int r = ch >> 3, c = (ch & 7) ^ (r & 7);
      gload_lds16(A + (size_t)(m0 + r) * CC + k0 + c * 8, &As[ch * 8]);
    }
    __syncthreads();
    bf16x8 af[4][2], bfr[4][2];
#pragma unroll
    for (int i = 0; i < 4; ++i) {
      int rA = waveM + i * 16 + l15;
      af[i][0] = *(const bf16x8*)&As[(rA * 8 + (quad ^ (rA & 7))) * 8];
      af[i][1] = *(const bf16x8*)&As[(rA * 8 + ((quad + 4) ^ (rA & 7))) * 8];
      int rB = waveN + i * 16 + l15;
      bfr[i][0] = *(const bf16x8*)&Bs[(rB * 8 + (quad ^ (rB & 7))) * 8];
      bfr[i][1] = *(const bf16x8*)&Bs[(rB * 8 + ((quad + 4) ^ (rB & 7))) * 8];
    }
#pragma unroll
    for (int mi = 0; mi < 4; ++mi)
#pragma unroll
      for (int ni = 0; ni < 4; ++ni) {
        acc[mi][ni] = __builtin_amdgcn_mfma_f32_16x16x32_bf16(
            af[mi][0], bfr[ni][0], acc[mi][ni], 0, 0, 0);
        acc[mi][ni] = __builtin_amdgcn_mfma_f32_16x16x32_bf16(
            af[mi][1], bfr[ni][1], acc[mi][ni], 0, 0, 0);
      }
    __syncthreads();
  }
  // epilogue: C/D col=lane&15, row=quad*4+reg; RoPE in-register for z<2.
  // z==0: scale = hd^-0.5 * log2(e) so attn3's softmax runs in base 2.
  const float scale = (z == 0) ? 0.125f * 1.44269504f : 1.0f;
#pragma unroll
  for (int mi = 0; mi < 4; ++mi) {
#pragma unroll
    for (int r = 0; r < 4; ++r) {
      int m = m0 + waveM + mi * 16 + quad * 4 + r;
      int l = m & (NN - 1);
      if (z == 2) {
#pragma unroll
        for (int ni = 0; ni < 4; ++ni)
          Out[(size_t)m * CC + n0 + waveN + ni * 16 + l15] = (bf16)acc[mi][ni][r];
      } else {
#pragma unroll
        for (int ni = 0; ni < 2; ++ni) {
          int col = n0 + waveN + ni * 16 + l15;
          int d = ni * 16 + l15;                 // head-local, in [0,32)
          float x1 = acc[mi][ni][r], x2 = acc[mi][ni + 2][r];
          float s1, c1, s2f, c2f;
          __sincosf(pos[l * HD + d], &s1, &c1);
          __sincosf(pos[l * HD + d + 32], &s2f, &c2f);
          Out[(size_t)m * CC + col]      = (bf16)((x1 * c1 - x2 * s1) * scale);
          Out[(size_t)m * CC + col + 32] = (bf16)((x2 * c2f + x1 * s2f) * scale);
        }
      }
    }
  }
}

// ---------------- K pack: MFMA-A-frag order. frag (ni,hf): elem[lane][j] =
// K[key=tile*64+ni*16+l15][d=hf*32+quad*8+j]   (A[m=l15][k=quad*8+j] layout)
__global__ __launch_bounds__(256)
void kpack_kernel(const bf16* __restrict__ Kp, bf16* __restrict__ Kpack) {
  int tix = blockIdx.x, h = blockIdx.y, b = blockIdx.z;
  int bh = b * HH + h;
#pragma unroll
  for (int p = 0; p < 2; ++p) {
    int sp = p * 256 + threadIdx.x;
    int fs = sp >> 6, lane = sp & 63, quad = (sp >> 4) & 3, l15 = sp & 15;
    int ni = fs >> 1, hf = fs & 1;
    bf16x8 v = *(const bf16x8*)&Kp[((size_t)(b * KVN + tix * 64 + ni * 16 + l15)) * CC
                                   + h * HD + hf * 32 + quad * 8];
    *(bf16x8*)&Kpack[(((size_t)(bh * 32 + tix)) * 8 + fs) * 512 + lane * 8] = v;
  }
}

// ---------------- V pack: V^T in A-frag order, pre-masked, + mask row (d=64).
__global__ __launch_bounds__(256)
void vpack_kernel(const bf16* __restrict__ Vp, const int* __restrict__ mask,
                  bf16* __restrict__ VpA, bf16* __restrict__ VpB) {
  __shared__ bf16 t[64][80];
  int tix = blockIdx.x, h = blockIdx.y, b = blockIdx.z;
  int j0 = tix * 64, bh = b * HH + h;
  const int* maskb = mask + b * KVN;
  int tid = threadIdx.x;
  int lr = tid >> 3, lc = (tid & 7) * 8;
  for (int p = 0; p < 2; ++p) {
    int j = lr + p * 32;
    int mv = maskb[j0 + j];
    bf16x8 v = *(const bf16x8*)&Vp[(size_t)(b * KVN + j0 + j) * CC + h * HD + lc];
#pragma unroll
    for (int uu = 0; uu < 8; ++uu) t[lc + uu][j] = mv ? v[uu] : (bf16)0.f;
  }
  __syncthreads();
  for (int p = 0; p < 3; ++p) {
    int sp = p * 256 + tid;
    if (sp < 640) {
      int fs = sp >> 6, lane = sp & 63, quad = (sp >> 4) & 3, l15 = sp & 15;
      int ni = fs >> 1, hf = fs & 1;
      bf16x8 v;
      if (ni < 4) {
        v = *(const bf16x8*)&t[ni * 16 + l15][hf * 32 + quad * 8];
      } else {
#pragma unroll
        for (int jj = 0; jj < 8; ++jj)
          v[jj] = (l15 == 0) ? (bf16)(float)maskb[j0 + hf * 32 + quad * 8 + jj]
                             : (bf16)0.f;
      }
      bf16* dst = (fs < 6) ? (VpA + (size_t)fs * (1 << 19))
                           : (VpB + (size_t)(fs - 6) * (1 << 19));
      *(bf16x8*)&dst[((size_t)(bh * 32 + tix)) * 512 + lane * 8] = v;
    }
  }
}

// ---------------- attention v5: 4-way KV split + base-2 softmax, merge with
// STATIC indexing only. Round-9 postmortem: `Oacc[gbase+gg]` with runtime
// gbase (rule #20) demoted the whole accumulator array to scratch --
// WRITE_SIZE 8MB->390MB, VGPR 116->84, MfmaUtil 8%. MERGE_PASS expands both
// passes with literal Oacc subscripts; occupancy lever (2 blocks -> 4
// blocks/CU via 38KB LDS) now acts on a non-spilling kernel.
#define MERGE_PASS(G0, G1)                                                    \
  {                                                                           \
    if (wave != 0) {                                                          \
      float* dst = mrg + (wave - 1) * 2560 + lane * 4;                        \
      _Pragma("unroll")                                                       \
      for (int ni = 0; ni < 5; ++ni) {                                        \
        *(f32x4*)&dst[ni * 256] = Oacc[G0][ni];                               \
        *(f32x4*)&dst[(5 + ni) * 256] = Oacc[G1][ni];                         \
      }                                                                       \
    }                                                                         \
    __syncthreads();                                                          \
    if (wave == 0) {                                                          \
      _Pragma("unroll")                                                       \
      for (int w = 0; w < 3; ++w) {                                           \
        float* src = mrg + w * 2560 + lane * 4;                               \
        _Pragma("unroll")                                                     \
        for (int ni = 0; ni < 5; ++ni) {                                      \
          f32x4 o0 = *(const f32x4*)&src[ni * 256];                           \
          f32x4 o1 = *(const f32x4*)&src[(5 + ni) * 256];                     \
          _Pragma("unroll")                                                   \
          for (int r = 0; r < 4; ++r) {                                       \
            Oacc[G0][ni][r] += o0[r];                                         \
            Oacc[G1][ni][r] += o1[r];                                         \
          }                                                                   \
        }                                                                     \
      }                                                                       \
      {                                                                       \
        float ls0 = __shfl(Oacc[G0][4][0], l15, 64);                          \
        float rn0 = 1.0f / ls0;                                               \
        float ls1 = __shfl(Oacc[G1][4][0], l15, 64);                          \
        float rn1 = 1.0f / ls1;                                               \
        _Pragma("unroll")                                                     \
        for (int ni = 0; ni < 4; ++ni) {                                      \
          bf16x4 ov0, ov1;                                                    \
          _Pragma("unroll")                                                   \
          for (int r = 0; r < 4; ++r) {                                       \
            ov0[r] = (bf16)(Oacc[G0][ni][r] * rn0);                           \
            ov1[r] = (bf16)(Oacc[G1][ni][r] * rn1);                           \
          }                                                                   \
          *(bf16x4*)&X[((size_t)(b * NN) + q0 + (G0) * 16 + l15) * CC         \
                       + h * HD + ni * 16 + quad * 4] = ov0;                  \
          *(bf16x4*)&X[((size_t)(b * NN) + q0 + (G1) * 16 + l15) * CC         \
                       + h * HD + ni * 16 + quad * 4] = ov1;                  \
        }                                                                     \
      }                                                                       \
    }                                                                         \
    __syncthreads();                                                          \
  }

__global__ __launch_bounds__(256, 3)
void attn3(const bf16* __restrict__ Qp, const bf16* __restrict__ Kpack,
           const bf16* __restrict__ VpA, const bf16* __restrict__ VpB,
           bf16* __restrict__ X) {
  __shared__ char smem[38912];      // [0,8K): per-wave P; [8K,38K): 3 merge slabs
  const int tid = threadIdx.x, wave = tid >> 6, lane = tid & 63;
  const int quad = lane >> 4, l15 = lane & 15;
  const int bid = blockIdx.x;
  const int u = bid & 7, s = bid >> 3;       // s in [0,128)
  const int bh = u * 4 + (s & 3);            // each XCD: 4 bh -> L2-local K/V
  const int qc = s >> 2;                     // 0..31
  const int b = bh >> 4, h = bh & 15;
  const int kh = wave;                       // 0..3: KV quarter
  const int q0 = qc * 64;
  const int sw = 2 * (l15 & 7);

  bf16* P = (bf16*)(smem + wave * 2048);
  float* mrg = (float*)(smem + 8192);

  bf16x8 qa[4][2];
#pragma unroll
  for (int g = 0; g < 4; ++g) {
    const bf16* qrow = Qp + ((size_t)(b * NN) + q0 + g * 16 + l15) * CC + h * HD;
    qa[g][0] = *(const bf16x8*)&qrow[quad * 8];
    qa[g][1] = *(const bf16x8*)&qrow[32 + quad * 8];
  }

  f32x4 Oacc[4][5] = {};
  const bf16* kbase = Kpack + (size_t)bh * 32 * 8 * 512;

  for (int it = 0; it < 8; ++it) {
    int t = kh * 8 + it;
    bf16x8 kb[8], vb[10];
#pragma unroll
    for (int fs = 0; fs < 8; ++fs)
      kb[fs] = *(const bf16x8*)&kbase[((size_t)t * 8 + fs) * 512 + lane * 8];
#pragma unroll
    for (int fs = 0; fs < 10; ++fs) {
      const bf16* vbs = (fs < 6) ? (VpA + (size_t)fs * (1 << 19))
                                 : (VpB + (size_t)(fs - 6) * (1 << 19));
      vb[fs] = *(const bf16x8*)&vbs[((size_t)(bh * 32 + t)) * 512 + lane * 8];
    }
#pragma unroll
    for (int g = 0; g < 4; ++g) {
      f32x4 sg[4];
      __builtin_amdgcn_s_setprio(1);
#pragma unroll
      for (int ni = 0; ni < 4; ++ni) {
        f32x4 zz = {};
        zz = __builtin_amdgcn_mfma_f32_16x16x32_bf16(kb[ni * 2], qa[g][0], zz, 0, 0, 0);
        zz = __builtin_amdgcn_mfma_f32_16x16x32_bf16(kb[ni * 2 + 1], qa[g][1], zz, 0, 0, 0);
        sg[ni] = zz;
      }
      __builtin_amdgcn_s_setprio(0);
#pragma unroll
      for (int ni = 0; ni < 4; ++ni) {
        bf16x4 pk;
#pragma unroll
        for (int r = 0; r < 4; ++r) pk[r] = (bf16)exp2f(sg[ni][r] - 5.7707802f);
        *(bf16x4*)&P[(l15 * 16 + ((ni * 4 + quad) ^ sw)) * 4] = pk;
      }
      bf16x8 pf0 = *(const bf16x8*)&P[(l15 * 16 + ((quad * 2) ^ sw)) * 4];
      bf16x8 pf1 = *(const bf16x8*)&P[(l15 * 16 + ((8 + quad * 2) ^ sw)) * 4];
      __builtin_amdgcn_s_setprio(1);
#pragma unroll
      for (int ni = 0; ni < 5; ++ni) {
        Oacc[g][ni] = __builtin_amdgcn_mfma_f32_16x16x32_bf16(vb[ni * 2], pf0, Oacc[g][ni], 0, 0, 0);
        Oacc[g][ni] = __builtin_amdgcn_mfma_f32_16x16x32_bf16(vb[ni * 2 + 1], pf1, Oacc[g][ni], 0, 0, 0);
      }
      __builtin_amdgcn_s_setprio(0);
    }
  }

  MERGE_PASS(0, 1)
  MERGE_PASS(2, 3)
}

// ---------------- projection GEMM: 64x128 tile, BK=64, 8-slot swizzle, grid 512
__global__ __launch_bounds__(256, 4)
void gemm_proj(const bf16* __restrict__ A, const bf16* __restrict__ Bt,
               float* __restrict__ Out) {
  __shared__ bf16 As[64 * 64];    // 8 KB
  __shared__ bf16 Bs[128 * 64];   // 16 KB
  const int bid = blockIdx.x;
  const int u = bid & 7, s = bid >> 3;        // s in [0,64)
  const int m0 = (u * 8 + (s >> 3)) * 64;
  const int n0 = (s & 7) * 128;
  const int tid = threadIdx.x;
  const int wave = tid >> 6, lane = tid & 63;
  const int quad = lane >> 4, l15 = lane & 15;
  const int waveM = (wave >> 1) * 32, waveN = (wave & 1) * 64;
  f32x4 acc[2][4] = {};

  for (int k0 = 0; k0 < CC; k0 += 64) {
#pragma unroll
    for (int p = 0; p < 2; ++p) {
      int ch = p * 256 + tid;
      int r = ch >> 3, c = (ch & 7) ^ (r & 7);
      gload_lds16(A + (size_t)(m0 + r) * CC + k0 + c * 8, &As[ch * 8]);
    }
#pragma unroll
    for (int p = 0; p < 4; ++p) {
      int ch = p * 256 + tid;
      int r = ch >> 3, c = (ch & 7) ^ (r & 7);
      gload_lds16(Bt + (size_t)(n0 + r) * CC + k0 + c * 8, &Bs[ch * 8]);
    }
    __syncthreads();
    bf16x8 af[2][2], bfr[4][2];
#pragma unroll
    for (int i = 0; i < 2; ++i) {
      int rA = waveM + i * 16 + l15;
      af[i][0] = *(const bf16x8*)&As[(rA * 8 + (quad ^ (rA & 7))) * 8];
      af[i][1] = *(const bf16x8*)&As[(rA * 8 + ((quad + 4) ^ (rA & 7))) * 8];
    }
#pragma unroll
    for (int i = 0; i < 4; ++i) {
      int rB = waveN + i * 16 + l15;
      bfr[i][0] = *(const bf16x8*)&Bs[(rB * 8 + (quad ^ (rB & 7))) * 8];
      bfr[i][1] = *(const bf16x8*)&Bs[(rB * 8 + ((quad + 4) ^ (rB & 7))) * 8];
    }
#pragma unroll
    for (int mi = 0; mi < 2; ++mi)
#pragma unroll
      for (int ni = 0; ni < 4; ++ni) {
        acc[mi][ni] = __builtin_amdgcn_mfma_f32_16x16x32_bf16(
            af[mi][0], bfr[ni][0], acc[mi][ni], 0, 0, 0);
        acc[mi][ni] = __builtin_amdgcn_mfma_f32_16x16x32_bf16(
            af[mi][1], bfr[ni][1], acc[mi][ni], 0, 0, 0);
      }
    __syncthreads();
  }
#pragma unroll
  for (int mi = 0; mi < 2; ++mi)
#pragma unroll
    for (int ni = 0; ni < 4; ++ni)
#pragma unroll
      for (int r = 0; r < 4; ++r) {
        int row = m0 + waveM + mi * 16 + quad * 4 + r;
        int col = n0 + waveN + ni * 16 + l15;
        Out[(size_t)row * CC + col] = acc[mi][ni][r];
      }
}

extern "C" void kernel_launch(void* const* d_in, const int* in_sizes, int n_in,
                              void* d_out, int out_size, void* d_ws, size_t ws_size,
                              hipStream_t stream) {
  const float* q    = (const float*)d_in[0];
  const float* k    = (const float*)d_in[1];
  const float* v    = (const float*)d_in[2];
  const int*   mask = (const int*)d_in[3];
  const float* pos  = (const float*)d_in[4];
  const float* qW   = (const float*)d_in[5];
  const float* kW   = (const float*)d_in[6];
  const float* vW   = (const float*)d_in[7];
  const float* pW   = (const float*)d_in[8];
  float* out = (float*)d_out;

  char* w = (char*)d_ws;
  const size_t MB = 1024 * 1024;
  // layout (<=48MB): Wt@0-8; Qp@8-16; Kp@16-24 (dead after kpack -> X aliases);
  // Vp@24-32 (dead after vpack); Abf@32-44 (12MB, dead after gemm_qkv ->
  // Kpack@32-40 and VpB@40-44 overwrite it); VpA@0-6 over dead qWt/kWt/vWt.
  bf16* Wt    = (bf16*)(w);
  bf16* Qp    = (bf16*)(w + 8 * MB);
  bf16* Kp    = (bf16*)(w + 16 * MB);
  bf16* Vp    = (bf16*)(w + 24 * MB);
  bf16* Abf   = (bf16*)(w + 32 * MB);   // 12 MB, live only through gemm_qkv
  bf16* Kpack = (bf16*)(w + 32 * MB);   // 8 MB, written after Abf is dead
  bf16* VpA   = (bf16*)(w);             // 6 MB over dead qWt/kWt/vWt
  bf16* VpB   = (bf16*)(w + 40 * MB);   // 4 MB, written after Abf is dead
  bf16* X     = (bf16*)(w + 16 * MB);   // aliases Kp

  wtrans<<<dim3(16, 16, 4), 256, 0, stream>>>(qW, kW, vW, pW, Wt);
  cvt_qkv<<<dim3(2048, 3), 256, 0, stream>>>(q, k, v, Abf);
  gemm_qkv<<<dim3(768), 256, 0, stream>>>(Abf, Wt, pos, Qp, Kp, Vp);
  kpack_kernel<<<dim3(KVN / 64, HH, BB), 256, 0, stream>>>(Kp, Kpack);
  vpack_kernel<<<dim3(KVN / 64, HH, BB), 256, 0, stream>>>(Vp, mask, VpA, VpB);
  attn3<<<dim3(1024), 256, 0, stream>>>(Qp, Kpack, VpA, VpB, X);
  gemm_proj<<<dim3(512), 256, 0, stream>>>(X, Wt + 3 * (size_t)CC * CC, out);
}

// Round 12
// 243.632 us; speedup vs baseline: 1.4134x; 1.3033x over previous
//
#include <hip/hip_runtime.h>
#include <hip/hip_bf16.h>

#define BB 2
#define NN 2048
#define KVN 2048
#define CC 1024
#define HH 16
#define HD 64

typedef __bf16 bf16;
typedef __attribute__((ext_vector_type(4))) __bf16 bf16x4;
typedef __attribute__((ext_vector_type(8))) __bf16 bf16x8;
typedef __attribute__((ext_vector_type(4))) float f32x4;

__device__ __forceinline__ void gload_lds16(const void* g, void* l) {
  __builtin_amdgcn_global_load_lds(
      (const __attribute__((address_space(1))) void*)g,
      (__attribute__((address_space(3))) void*)l, 16, 0, 0);
}

// ---------------- batched weight transpose: Wt[z][c][r] = (bf16)W_z[r][c]
__global__ __launch_bounds__(256)
void wtrans(const float* __restrict__ qW, const float* __restrict__ kW,
            const float* __restrict__ vW, const float* __restrict__ pW,
            bf16* __restrict__ Wt) {
  __shared__ bf16 t[64][72];
  const float* in = (blockIdx.z == 0) ? qW : (blockIdx.z == 1) ? kW
                    : (blockIdx.z == 2) ? vW : pW;
  bf16* out = Wt + (size_t)blockIdx.z * CC * CC;
  int r0 = blockIdx.y * 64, c0 = blockIdx.x * 64;
  int tid = threadIdx.x;
  int lr = tid >> 3, lc = (tid & 7) * 8;
  for (int p = 0; p < 2; ++p) {
    int rr = lr + p * 32;
    const float* src = &in[(size_t)(r0 + rr) * CC + c0 + lc];
    float4 a = *(const float4*)src;
    float4 b = *(const float4*)(src + 4);
    t[lc + 0][rr] = (bf16)a.x; t[lc + 1][rr] = (bf16)a.y;
    t[lc + 2][rr] = (bf16)a.z; t[lc + 3][rr] = (bf16)a.w;
    t[lc + 4][rr] = (bf16)b.x; t[lc + 5][rr] = (bf16)b.y;
    t[lc + 6][rr] = (bf16)b.z; t[lc + 7][rr] = (bf16)b.w;
  }
  __syncthreads();
  for (int p = 0; p < 2; ++p) {
    int rr = lr + p * 32;
    *(bf16x8*)&out[(size_t)(c0 + rr) * CC + r0 + lc] = *(const bf16x8*)&t[rr][lc];
  }
}

// ---------------- qkv fp32 -> bf16 prepass: Abf[z][row][col], 36 MB HBM (~6us)
__global__ __launch_bounds__(256)
void cvt_qkv(const float* __restrict__ qin, const float* __restrict__ kin,
             const float* __restrict__ vin, bf16* __restrict__ Abf) {
  const int z = blockIdx.y;
  const float* s = (z == 0) ? qin : (z == 1) ? kin : vin;
  size_t off = ((size_t)blockIdx.x * 256 + threadIdx.x) * 8;  // < 4194304
  float4 a = *(const float4*)(s + off);
  float4 b = *(const float4*)(s + off + 4);
  bf16x8 t;
  t[0] = (bf16)a.x; t[1] = (bf16)a.y; t[2] = (bf16)a.z; t[3] = (bf16)a.w;
  t[4] = (bf16)b.x; t[5] = (bf16)b.y; t[6] = (bf16)b.z; t[7] = (bf16)b.w;
  *(bf16x8*)&Abf[(size_t)z * ((size_t)BB * NN * CC) + off] = t;
}

// ---------------- merged QKV GEMM: 128x128 tile, BK=64 (round-8 v8, kept).
// A pre-converted bf16 -> both operands on the proven gload_lds 8-slot path.
// z==0 scale folds log2(e): attn3 then uses exp2 (1 VALU op) for softmax.
__global__ __launch_bounds__(256, 3)
void gemm_qkv(const bf16* __restrict__ Abf, const bf16* __restrict__ Wt,
              const float* __restrict__ pos, bf16* __restrict__ Qp,
              bf16* __restrict__ Kp, bf16* __restrict__ Vp) {
  __shared__ bf16 As[128 * 64];   // 16 KB, chunks of 8: L = r*8 + (c^(r&7))
  __shared__ bf16 Bs[128 * 64];   // 16 KB, same swizzle
  const int bid = blockIdx.x;
  const int u = bid & 7, s = bid >> 3;       // s in [0,96)
  const int nblk = s >> 2;                   // 0..23
  const int m0 = (u * 4 + (s & 3)) * 128;
  const int z = nblk >> 3;
  const int n0 = (nblk & 7) * 128;
  const bf16* A = Abf + (size_t)z * ((size_t)BB * NN * CC);
  const bf16* Bt = Wt + (size_t)z * CC * CC;
  bf16* Out = (z == 0) ? Qp : (z == 1) ? Kp : Vp;
  const int tid = threadIdx.x;
  const int wave = tid >> 6, lane = tid & 63;
  const int quad = lane >> 4, l15 = lane & 15;
  const int waveM = (wave >> 1) * 64, waveN = (wave & 1) * 64;
  f32x4 acc[4][4] = {};

  for (int k0 = 0; k0 < CC; k0 += 64) {
#pragma unroll
    for (int p = 0; p < 4; ++p) {   // B: 1024 bf16-chunks, async direct-to-LDS
      int ch = p * 256 + tid;
      int r = ch >> 3, c = (ch & 7) ^ (r & 7);
      gload_lds16(Bt + (size_t)(n0 + r) * CC + k0 + c * 8, &Bs[ch * 8]);
    }
#pragma unroll
    for (int p = 0; p < 4; ++p) {   // A: same proven path, bf16
      int ch = p * 256 + tid;
      int r = ch >> 3, c = (ch & 7) ^ (r & 7);
      gload_lds16(A + (size_t)(m0 + r) * CC + k0 + c * 8, &As[ch * 8]);
    }
    __syncthreads();
    bf16x8 af[4][2], bfr[4][2];
#pragma unroll
    for (int i = 0; i < 4; ++i) {
      int rA = waveM + i * 16 + l15;
      af[i][0] = *(const bf16x8*)&As[(rA * 8 + (quad ^ (rA & 7))) * 8];
      af[i][1] = *(const bf16x8*)&As[(rA * 8 + ((quad + 4) ^ (rA & 7))) * 8];
      int rB = waveN + i * 16 + l15;
      bfr[i][0] = *(const bf16x8*)&Bs[(rB * 8 + (quad ^ (rB & 7))) * 8];
      bfr[i][1] = *(const bf16x8*)&Bs[(rB * 8 + ((quad + 4) ^ (rB & 7))) * 8];
    }
#pragma unroll
    for (int mi = 0; mi < 4; ++mi)
#pragma unroll
      for (int ni = 0; ni < 4; ++ni) {
        acc[mi][ni] = __builtin_amdgcn_mfma_f32_16x16x32_bf16(
            af[mi][0], bfr[ni][0], acc[mi][ni], 0, 0, 0);
        acc[mi][ni] = __builtin_amdgcn_mfma_f32_16x16x32_bf16(
            af[mi][1], bfr[ni][1], acc[mi][ni], 0, 0, 0);
      }
    __syncthreads();
  }
  // epilogue: C/D col=lane&15, row=quad*4+reg; RoPE in-register for z<2.
  // z==0: scale = hd^-0.5 * log2(e) so attn3's softmax runs in base 2.
  const float scale = (z == 0) ? 0.125f * 1.44269504f : 1.0f;
#pragma unroll
  for (int mi = 0; mi < 4; ++mi) {
#pragma unroll
    for (int r = 0; r < 4; ++r) {
      int m = m0 + waveM + mi * 16 + quad * 4 + r;
      int l = m & (NN - 1);
      if (z == 2) {
#pragma unroll
        for (int ni = 0; ni < 4; ++ni)
          Out[(size_t)m * CC + n0 + waveN + ni * 16 + l15] = (bf16)acc[mi][ni][r];
      } else {
#pragma unroll
        for (int ni = 0; ni < 2; ++ni) {
          int col = n0 + waveN + ni * 16 + l15;
          int d = ni * 16 + l15;                 // head-local, in [0,32)
          float x1 = acc[mi][ni][r], x2 = acc[mi][ni + 2][r];
          float s1, c1, s2f, c2f;
          __sincosf(pos[l * HD + d], &s1, &c1);
          __sincosf(pos[l * HD + d + 32], &s2f, &c2f);
          Out[(size_t)m * CC + col]      = (bf16)((x1 * c1 - x2 * s1) * scale);
          Out[(size_t)m * CC + col + 32] = (bf16)((x2 * c2f + x1 * s2f) * scale);
        }
      }
    }
  }
}

// ---------------- K pack: MFMA-A-frag order. frag (ni,hf): elem[lane][j] =
// K[key=tile*64+ni*16+l15][d=hf*32+quad*8+j]   (A[m=l15][k=quad*8+j] layout)
__global__ __launch_bounds__(256)
void kpack_kernel(const bf16* __restrict__ Kp, bf16* __restrict__ Kpack) {
  int tix = blockIdx.x, h = blockIdx.y, b = blockIdx.z;
  int bh = b * HH + h;
#pragma unroll
  for (int p = 0; p < 2; ++p) {
    int sp = p * 256 + threadIdx.x;
    int fs = sp >> 6, lane = sp & 63, quad = (sp >> 4) & 3, l15 = sp & 15;
    int ni = fs >> 1, hf = fs & 1;
    bf16x8 v = *(const bf16x8*)&Kp[((size_t)(b * KVN + tix * 64 + ni * 16 + l15)) * CC
                                   + h * HD + hf * 32 + quad * 8];
    *(bf16x8*)&Kpack[(((size_t)(bh * 32 + tix)) * 8 + fs) * 512 + lane * 8] = v;
  }
}

// ---------------- V pack: V^T in A-frag order, pre-masked, + mask row (d=64).
__global__ __launch_bounds__(256)
void vpack_kernel(const bf16* __restrict__ Vp, const int* __restrict__ mask,
                  bf16* __restrict__ VpA, bf16* __restrict__ VpB) {
  __shared__ bf16 t[64][80];
  int tix = blockIdx.x, h = blockIdx.y, b = blockIdx.z;
  int j0 = tix * 64, bh = b * HH + h;
  const int* maskb = mask + b * KVN;
  int tid = threadIdx.x;
  int lr = tid >> 3, lc = (tid & 7) * 8;
  for (int p = 0; p < 2; ++p) {
    int j = lr + p * 32;
    int mv = maskb[j0 + j];
    bf16x8 v = *(const bf16x8*)&Vp[(size_t)(b * KVN + j0 + j) * CC + h * HD + lc];
#pragma unroll
    for (int uu = 0; uu < 8; ++uu) t[lc + uu][j] = mv ? v[uu] : (bf16)0.f;
  }
  __syncthreads();
  for (int p = 0; p < 3; ++p) {
    int sp = p * 256 + tid;
    if (sp < 640) {
      int fs = sp >> 6, lane = sp & 63, quad = (sp >> 4) & 3, l15 = sp & 15;
      int ni = fs >> 1, hf = fs & 1;
      bf16x8 v;
      if (ni < 4) {
        v = *(const bf16x8*)&t[ni * 16 + l15][hf * 32 + quad * 8];
      } else {
#pragma unroll
        for (int jj = 0; jj < 8; ++jj)
          v[jj] = (l15 == 0) ? (bf16)(float)maskb[j0 + hf * 32 + quad * 8 + jj]
                             : (bf16)0.f;
      }
      bf16* dst = (fs < 6) ? (VpA + (size_t)fs * (1 << 19))
                           : (VpB + (size_t)(fs - 6) * (1 << 19));
      *(bf16x8*)&dst[((size_t)(bh * 32 + tix)) * 512 + lane * 8] = v;
    }
  }
}

// ---------------- attention v6: 4-way KV split + base-2 softmax + static
// two-pass merge. Round-10 postmortem: the spill was the launch_bounds(256,3)
// VGPR cap (~168) vs the kernel's ~190-200 peak live set (Oacc 80 + kb 32 +
// vb 40 + qa 32), NOT dynamic indexing -- round 8 fit in 116 regs at (256,2).
// (256,2): cap 256, compiler allocates ~116-135. launch_bounds' 2nd arg is a
// reg-cap guarantee, not a residency limit: at VGPR<=128 the HW gives 16
// waves/CU, and LDS 38912x4 = 155.6K <= 160K -> 4 blocks/CU co-reside anyway.
// Downside bounded: if VGPR >128 -> 2 blocks/CU = round-8 baseline.
#define MERGE_PASS(G0, G1)                                                    \
  {                                                                           \
    if (wave != 0) {                                                          \
      float* dst = mrg + (wave - 1) * 2560 + lane * 4;                        \
      _Pragma("unroll")                                                       \
      for (int ni = 0; ni < 5; ++ni) {                                        \
        *(f32x4*)&dst[ni * 256] = Oacc[G0][ni];                               \
        *(f32x4*)&dst[(5 + ni) * 256] = Oacc[G1][ni];                         \
      }                                                                       \
    }                                                                         \
    __syncthreads();                                                          \
    if (wave == 0) {                                                          \
      _Pragma("unroll")                                                       \
      for (int w = 0; w < 3; ++w) {                                           \
        float* src = mrg + w * 2560 + lane * 4;                               \
        _Pragma("unroll")                                                     \
        for (int ni = 0; ni < 5; ++ni) {                                      \
          f32x4 o0 = *(const f32x4*)&src[ni * 256];                           \
          f32x4 o1 = *(const f32x4*)&src[(5 + ni) * 256];                     \
          _Pragma("unroll")                                                   \
          for (int r = 0; r < 4; ++r) {                                       \
            Oacc[G0][ni][r] += o0[r];                                         \
            Oacc[G1][ni][r] += o1[r];                                         \
          }                                                                   \
        }                                                                     \
      }                                                                       \
      {                                                                       \
        float ls0 = __shfl(Oacc[G0][4][0], l15, 64);                          \
        float rn0 = 1.0f / ls0;                                               \
        float ls1 = __shfl(Oacc[G1][4][0], l15, 64);                          \
        float rn1 = 1.0f / ls1;                                               \
        _Pragma("unroll")                                                     \
        for (int ni = 0; ni < 4; ++ni) {                                      \
          bf16x4 ov0, ov1;                                                    \
          _Pragma("unroll")                                                   \
          for (int r = 0; r < 4; ++r) {                                       \
            ov0[r] = (bf16)(Oacc[G0][ni][r] * rn0);                           \
            ov1[r] = (bf16)(Oacc[G1][ni][r] * rn1);                           \
          }                                                                   \
          *(bf16x4*)&X[((size_t)(b * NN) + q0 + (G0) * 16 + l15) * CC         \
                       + h * HD + ni * 16 + quad * 4] = ov0;                  \
          *(bf16x4*)&X[((size_t)(b * NN) + q0 + (G1) * 16 + l15) * CC         \
                       + h * HD + ni * 16 + quad * 4] = ov1;                  \
        }                                                                     \
      }                                                                       \
    }                                                                         \
    __syncthreads();                                                          \
  }

__global__ __launch_bounds__(256, 2)
void attn3(const bf16* __restrict__ Qp, const bf16* __restrict__ Kpack,
           const bf16* __restrict__ VpA, const bf16* __restrict__ VpB,
           bf16* __restrict__ X) {
  __shared__ char smem[38912];      // [0,8K): per-wave P; [8K,38K): 3 merge slabs
  const int tid = threadIdx.x, wave = tid >> 6, lane = tid & 63;
  const int quad = lane >> 4, l15 = lane & 15;
  const int bid = blockIdx.x;
  const int u = bid & 7, s = bid >> 3;       // s in [0,128)
  const int bh = u * 4 + (s & 3);            // each XCD: 4 bh -> L2-local K/V
  const int qc = s >> 2;                     // 0..31
  const int b = bh >> 4, h = bh & 15;
  const int kh = wave;                       // 0..3: KV quarter
  const int q0 = qc * 64;
  const int sw = 2 * (l15 & 7);

  bf16* P = (bf16*)(smem + wave * 2048);
  float* mrg = (float*)(smem + 8192);

  bf16x8 qa[4][2];
#pragma unroll
  for (int g = 0; g < 4; ++g) {
    const bf16* qrow = Qp + ((size_t)(b * NN) + q0 + g * 16 + l15) * CC + h * HD;
    qa[g][0] = *(const bf16x8*)&qrow[quad * 8];
    qa[g][1] = *(const bf16x8*)&qrow[32 + quad * 8];
  }

  f32x4 Oacc[4][5] = {};
  const bf16* kbase = Kpack + (size_t)bh * 32 * 8 * 512;

  for (int it = 0; it < 8; ++it) {
    int t = kh * 8 + it;
    bf16x8 kb[8], vb[10];
#pragma unroll
    for (int fs = 0; fs < 8; ++fs)
      kb[fs] = *(const bf16x8*)&kbase[((size_t)t * 8 + fs) * 512 + lane * 8];
#pragma unroll
    for (int fs = 0; fs < 10; ++fs) {
      const bf16* vbs = (fs < 6) ? (VpA + (size_t)fs * (1 << 19))
                                 : (VpB + (size_t)(fs - 6) * (1 << 19));
      vb[fs] = *(const bf16x8*)&vbs[((size_t)(bh * 32 + t)) * 512 + lane * 8];
    }
#pragma unroll
    for (int g = 0; g < 4; ++g) {
      f32x4 sg[4];
      __builtin_amdgcn_s_setprio(1);
#pragma unroll
      for (int ni = 0; ni < 4; ++ni) {
        f32x4 zz = {};
        zz = __builtin_amdgcn_mfma_f32_16x16x32_bf16(kb[ni * 2], qa[g][0], zz, 0, 0, 0);
        zz = __builtin_amdgcn_mfma_f32_16x16x32_bf16(kb[ni * 2 + 1], qa[g][1], zz, 0, 0, 0);
        sg[ni] = zz;
      }
      __builtin_amdgcn_s_setprio(0);
#pragma unroll
      for (int ni = 0; ni < 4; ++ni) {
        bf16x4 pk;
#pragma unroll
        for (int r = 0; r < 4; ++r) pk[r] = (bf16)exp2f(sg[ni][r] - 5.7707802f);
        *(bf16x4*)&P[(l15 * 16 + ((ni * 4 + quad) ^ sw)) * 4] = pk;
      }
      bf16x8 pf0 = *(const bf16x8*)&P[(l15 * 16 + ((quad * 2) ^ sw)) * 4];
      bf16x8 pf1 = *(const bf16x8*)&P[(l15 * 16 + ((8 + quad * 2) ^ sw)) * 4];
      __builtin_amdgcn_s_setprio(1);
#pragma unroll
      for (int ni = 0; ni < 5; ++ni) {
        Oacc[g][ni] = __builtin_amdgcn_mfma_f32_16x16x32_bf16(vb[ni * 2], pf0, Oacc[g][ni], 0, 0, 0);
        Oacc[g][ni] = __builtin_amdgcn_mfma_f32_16x16x32_bf16(vb[ni * 2 + 1], pf1, Oacc[g][ni], 0, 0, 0);
      }
      __builtin_amdgcn_s_setprio(0);
    }
  }

  MERGE_PASS(0, 1)
  MERGE_PASS(2, 3)
}

// ---------------- projection GEMM: 64x128 tile, BK=64, 8-slot swizzle, grid 512
__global__ __launch_bounds__(256, 4)
void gemm_proj(const bf16* __restrict__ A, const bf16* __restrict__ Bt,
               float* __restrict__ Out) {
  __shared__ bf16 As[64 * 64];    // 8 KB
  __shared__ bf16 Bs[128 * 64];   // 16 KB
  const int bid = blockIdx.x;
  const int u = bid & 7, s = bid >> 3;        // s in [0,64)
  const int m0 = (u * 8 + (s >> 3)) * 64;
  const int n0 = (s & 7) * 128;
  const int tid = threadIdx.x;
  const int wave = tid >> 6, lane = tid & 63;
  const int quad = lane >> 4, l15 = lane & 15;
  const int waveM = (wave >> 1) * 32, waveN = (wave & 1) * 64;
  f32x4 acc[2][4] = {};

  for (int k0 = 0; k0 < CC; k0 += 64) {
#pragma unroll
    for (int p = 0; p < 2; ++p) {
      int ch = p * 256 + tid;
      int r = ch >> 3, c = (ch & 7) ^ (r & 7);
      gload_lds16(A + (size_t)(m0 + r) * CC + k0 + c * 8, &As[ch * 8]);
    }
#pragma unroll
    for (int p = 0; p < 4; ++p) {
      int ch = p * 256 + tid;
      int r = ch >> 3, c = (ch & 7) ^ (r & 7);
      gload_lds16(Bt + (size_t)(n0 + r) * CC + k0 + c * 8, &Bs[ch * 8]);
    }
    __syncthreads();
    bf16x8 af[2][2], bfr[4][2];
#pragma unroll
    for (int i = 0; i < 2; ++i) {
      int rA = waveM + i * 16 + l15;
      af[i][0] = *(const bf16x8*)&As[(rA * 8 + (quad ^ (rA & 7))) * 8];
      af[i][1] = *(const bf16x8*)&As[(rA * 8 + ((quad + 4) ^ (rA & 7))) * 8];
    }
#pragma unroll
    for (int i = 0; i < 4; ++i) {
      int rB = waveN + i * 16 + l15;
      bfr[i][0] = *(const bf16x8*)&Bs[(rB * 8 + (quad ^ (rB & 7))) * 8];
      bfr[i][1] = *(const bf16x8*)&Bs[(rB * 8 + ((quad + 4) ^ (rB & 7))) * 8];
    }
#pragma unroll
    for (int mi = 0; mi < 2; ++mi)
#pragma unroll
      for (int ni = 0; ni < 4; ++ni) {
        acc[mi][ni] = __builtin_amdgcn_mfma_f32_16x16x32_bf16(
            af[mi][0], bfr[ni][0], acc[mi][ni], 0, 0, 0);
        acc[mi][ni] = __builtin_amdgcn_mfma_f32_16x16x32_bf16(
            af[mi][1], bfr[ni][1], acc[mi][ni], 0, 0, 0);
      }
    __syncthreads();
  }
#pragma unroll
  for (int mi = 0; mi < 2; ++mi)
#pragma unroll
    for (int ni = 0; ni < 4; ++ni)
#pragma unroll
      for (int r = 0; r < 4; ++r) {
        int row = m0 + waveM + mi * 16 + quad * 4 + r;
        int col = n0 + waveN + ni * 16 + l15;
        Out[(size_t)row * CC + col] = acc[mi][ni][r];
      }
}

extern "C" void kernel_launch(void* const* d_in, const int* in_sizes, int n_in,
                              void* d_out, int out_size, void* d_ws, size_t ws_size,
                              hipStream_t stream) {
  const float* q    = (const float*)d_in[0];
  const float* k    = (const float*)d_in[1];
  const float* v    = (const float*)d_in[2];
  const int*   mask = (const int*)d_in[3];
  const float* pos  = (const float*)d_in[4];
  const float* qW   = (const float*)d_in[5];
  const float* kW   = (const float*)d_in[6];
  const float* vW   = (const float*)d_in[7];
  const float* pW   = (const float*)d_in[8];
  float* out = (float*)d_out;

  char* w = (char*)d_ws;
  const size_t MB = 1024 * 1024;
  // layout (<=48MB): Wt@0-8; Qp@8-16; Kp@16-24 (dead after kpack -> X aliases);
  // Vp@24-32 (dead after vpack); Abf@32-44 (12MB, dead after gemm_qkv ->
  // Kpack@32-40 and VpB@40-44 overwrite it); VpA@0-6 over dead qWt/kWt/vWt.
  bf16* Wt    = (bf16*)(w);
  bf16* Qp    = (bf16*)(w + 8 * MB);
  bf16* Kp    = (bf16*)(w + 16 * MB);
  bf16* Vp    = (bf16*)(w + 24 * MB);
  bf16* Abf   = (bf16*)(w + 32 * MB);   // 12 MB, live only through gemm_qkv
  bf16* Kpack = (bf16*)(w + 32 * MB);   // 8 MB, written after Abf is dead
  bf16* VpA   = (bf16*)(w);             // 6 MB over dead qWt/kWt/vWt
  bf16* VpB   = (bf16*)(w + 40 * MB);   // 4 MB, written after Abf is dead
  bf16* X     = (bf16*)(w + 16 * MB);   // aliases Kp

  wtrans<<<dim3(16, 16, 4), 256, 0, stream>>>(qW, kW, vW, pW, Wt);
  cvt_qkv<<<dim3(2048, 3), 256, 0, stream>>>(q, k, v, Abf);
  gemm_qkv<<<dim3(768), 256, 0, stream>>>(Abf, Wt, pos, Qp, Kp, Vp);
  kpack_kernel<<<dim3(KVN / 64, HH, BB), 256, 0, stream>>>(Kp, Kpack);
  vpack_kernel<<<dim3(KVN / 64, HH, BB), 256, 0, stream>>>(Vp, mask, VpA, VpB);
  attn3<<<dim3(1024), 256, 0, stream>>>(Qp, Kpack, VpA, VpB, X);
  gemm_proj<<<dim3(512), 256, 0, stream>>>(X, Wt + 3 * (size_t)CC * CC, out);
}

// Round 13
// 215.026 us; speedup vs baseline: 1.6014x; 1.1330x over previous
//
#include <hip/hip_runtime.h>
#include <hip/hip_bf16.h>

#define BB 2
#define NN 2048
#define KVN 2048
#define CC 1024
#define HH 16
#define HD 64

typedef __bf16 bf16;
typedef __attribute__((ext_vector_type(4))) __bf16 bf16x4;
typedef __attribute__((ext_vector_type(8))) __bf16 bf16x8;
typedef __attribute__((ext_vector_type(4))) float f32x4;

__device__ __forceinline__ void gload_lds16(const void* g, void* l) {
  __builtin_amdgcn_global_load_lds(
      (const __attribute__((address_space(1))) void*)g,
      (__attribute__((address_space(3))) void*)l, 16, 0, 0);
}

__device__ __forceinline__ float exp2_raw(float x) {
  float r;
  asm("v_exp_f32 %0, %1" : "=v"(r) : "v"(x));   // D = 2^S0, 1 VALU op
  return r;
}

// ---------------- batched weight transpose: Wt[z][c][r] = (bf16)W_z[r][c]
__global__ __launch_bounds__(256)
void wtrans(const float* __restrict__ qW, const float* __restrict__ kW,
            const float* __restrict__ vW, const float* __restrict__ pW,
            bf16* __restrict__ Wt) {
  __shared__ bf16 t[64][72];
  const float* in = (blockIdx.z == 0) ? qW : (blockIdx.z == 1) ? kW
                    : (blockIdx.z == 2) ? vW : pW;
  bf16* out = Wt + (size_t)blockIdx.z * CC * CC;
  int r0 = blockIdx.y * 64, c0 = blockIdx.x * 64;
  int tid = threadIdx.x;
  int lr = tid >> 3, lc = (tid & 7) * 8;
  for (int p = 0; p < 2; ++p) {
    int rr = lr + p * 32;
    const float* src = &in[(size_t)(r0 + rr) * CC + c0 + lc];
    float4 a = *(const float4*)src;
    float4 b = *(const float4*)(src + 4);
    t[lc + 0][rr] = (bf16)a.x; t[lc + 1][rr] = (bf16)a.y;
    t[lc + 2][rr] = (bf16)a.z; t[lc + 3][rr] = (bf16)a.w;
    t[lc + 4][rr] = (bf16)b.x; t[lc + 5][rr] = (bf16)b.y;
    t[lc + 6][rr] = (bf16)b.z; t[lc + 7][rr] = (bf16)b.w;
  }
  __syncthreads();
  for (int p = 0; p < 2; ++p) {
    int rr = lr + p * 32;
    *(bf16x8*)&out[(size_t)(c0 + rr) * CC + r0 + lc] = *(const bf16x8*)&t[rr][lc];
  }
}

// ---------------- qkv fp32 -> bf16 prepass: Abf[z][row][col], 36 MB HBM (~6us)
__global__ __launch_bounds__(256)
void cvt_qkv(const float* __restrict__ qin, const float* __restrict__ kin,
             const float* __restrict__ vin, bf16* __restrict__ Abf) {
  const int z = blockIdx.y;
  const float* s = (z == 0) ? qin : (z == 1) ? kin : vin;
  size_t off = ((size_t)blockIdx.x * 256 + threadIdx.x) * 8;  // < 4194304
  float4 a = *(const float4*)(s + off);
  float4 b = *(const float4*)(s + off + 4);
  bf16x8 t;
  t[0] = (bf16)a.x; t[1] = (bf16)a.y; t[2] = (bf16)a.z; t[3] = (bf16)a.w;
  t[4] = (bf16)b.x; t[5] = (bf16)b.y; t[6] = (bf16)b.z; t[7] = (bf16)b.w;
  *(bf16x8*)&Abf[(size_t)z * ((size_t)BB * NN * CC) + off] = t;
}

// ---------------- merged QKV GEMM: 128x128 tile, BK=64 (round-8 v8, kept).
// A pre-converted bf16 -> both operands on the proven gload_lds 8-slot path.
// z==0 scale folds log2(e): attn3 then uses raw v_exp_f32 for base-2 softmax.
__global__ __launch_bounds__(256, 3)
void gemm_qkv(const bf16* __restrict__ Abf, const bf16* __restrict__ Wt,
              const float* __restrict__ pos, bf16* __restrict__ Qp,
              bf16* __restrict__ Kp, bf16* __restrict__ Vp) {
  __shared__ bf16 As[128 * 64];   // 16 KB, chunks of 8: L = r*8 + (c^(r&7))
  __shared__ bf16 Bs[128 * 64];   // 16 KB, same swizzle
  const int bid = blockIdx.x;
  const int u = bid & 7, s = bid >> 3;       // s in [0,96)
  const int nblk = s >> 2;                   // 0..23
  const int m0 = (u * 4 + (s & 3)) * 128;
  const int z = nblk >> 3;
  const int n0 = (nblk & 7) * 128;
  const bf16* A = Abf + (size_t)z * ((size_t)BB * NN * CC);
  const bf16* Bt = Wt + (size_t)z * CC * CC;
  bf16* Out = (z == 0) ? Qp : (z == 1) ? Kp : Vp;
  const int tid = threadIdx.x;
  const int wave = tid >> 6, lane = tid & 63;
  const int quad = lane >> 4, l15 = lane & 15;
  const int waveM = (wave >> 1) * 64, waveN = (wave & 1) * 64;
  f32x4 acc[4][4] = {};

  for (int k0 = 0; k0 < CC; k0 += 64) {
#pragma unroll
    for (int p = 0; p < 4; ++p) {   // B: 1024 bf16-chunks, async direct-to-LDS
      int ch = p * 256 + tid;
      int r = ch >> 3, c = (ch & 7) ^ (r & 7);
      gload_lds16(Bt + (size_t)(n0 + r) * CC + k0 + c * 8, &Bs[ch * 8]);
    }
#pragma unroll
    for (int p = 0; p < 4; ++p) {   // A: same proven path, bf16
      int ch = p * 256 + tid;
      int r = ch >> 3, c = (ch & 7) ^ (r & 7);
      gload_lds16(A + (size_t)(m0 + r) * CC + k0 + c * 8, &As[ch * 8]);
    }
    __syncthreads();
    bf16x8 af[4][2], bfr[4][2];
#pragma unroll
    for (int i = 0; i < 4; ++i) {
      int rA = waveM + i * 16 + l15;
      af[i][0] = *(const bf16x8*)&As[(rA * 8 + (quad ^ (rA & 7))) * 8];
      af[i][1] = *(const bf16x8*)&As[(rA * 8 + ((quad + 4) ^ (rA & 7))) * 8];
      int rB = waveN + i * 16 + l15;
      bfr[i][0] = *(const bf16x8*)&Bs[(rB * 8 + (quad ^ (rB & 7))) * 8];
      bfr[i][1] = *(const bf16x8*)&Bs[(rB * 8 + ((quad + 4) ^ (rB & 7))) * 8];
    }
#pragma unroll
    for (int mi = 0; mi < 4; ++mi)
#pragma unroll
      for (int ni = 0; ni < 4; ++ni) {
        acc[mi][ni] = __builtin_amdgcn_mfma_f32_16x16x32_bf16(
            af[mi][0], bfr[ni][0], acc[mi][ni], 0, 0, 0);
        acc[mi][ni] = __builtin_amdgcn_mfma_f32_16x16x32_bf16(
            af[mi][1], bfr[ni][1], acc[mi][ni], 0, 0, 0);
      }
    __syncthreads();
  }
  // epilogue: C/D col=lane&15, row=quad*4+reg; RoPE in-register for z<2.
  // z==0: scale = hd^-0.5 * log2(e) so attn3's softmax runs in base 2.
  const float scale = (z == 0) ? 0.125f * 1.44269504f : 1.0f;
#pragma unroll
  for (int mi = 0; mi < 4; ++mi) {
#pragma unroll
    for (int r = 0; r < 4; ++r) {
      int m = m0 + waveM + mi * 16 + quad * 4 + r;
      int l = m & (NN - 1);
      if (z == 2) {
#pragma unroll
        for (int ni = 0; ni < 4; ++ni)
          Out[(size_t)m * CC + n0 + waveN + ni * 16 + l15] = (bf16)acc[mi][ni][r];
      } else {
#pragma unroll
        for (int ni = 0; ni < 2; ++ni) {
          int col = n0 + waveN + ni * 16 + l15;
          int d = ni * 16 + l15;                 // head-local, in [0,32)
          float x1 = acc[mi][ni][r], x2 = acc[mi][ni + 2][r];
          float s1, c1, s2f, c2f;
          __sincosf(pos[l * HD + d], &s1, &c1);
          __sincosf(pos[l * HD + d + 32], &s2f, &c2f);
          Out[(size_t)m * CC + col]      = (bf16)((x1 * c1 - x2 * s1) * scale);
          Out[(size_t)m * CC + col + 32] = (bf16)((x2 * c2f + x1 * s2f) * scale);
        }
      }
    }
  }
}

// ---------------- K pack: MFMA-A-frag order. frag (ni,hf): elem[lane][j] =
// K[key=tile*64+ni*16+l15][d=hf*32+quad*8+j]   (A[m=l15][k=quad*8+j] layout)
__global__ __launch_bounds__(256)
void kpack_kernel(const bf16* __restrict__ Kp, bf16* __restrict__ Kpack) {
  int tix = blockIdx.x, h = blockIdx.y, b = blockIdx.z;
  int bh = b * HH + h;
#pragma unroll
  for (int p = 0; p < 2; ++p) {
    int sp = p * 256 + threadIdx.x;
    int fs = sp >> 6, lane = sp & 63, quad = (sp >> 4) & 3, l15 = sp & 15;
    int ni = fs >> 1, hf = fs & 1;
    bf16x8 v = *(const bf16x8*)&Kp[((size_t)(b * KVN + tix * 64 + ni * 16 + l15)) * CC
                                   + h * HD + hf * 32 + quad * 8];
    *(bf16x8*)&Kpack[(((size_t)(bh * 32 + tix)) * 8 + fs) * 512 + lane * 8] = v;
  }
}

// ---------------- V pack: V^T in A-frag order, pre-masked, + mask row (d=64).
__global__ __launch_bounds__(256)
void vpack_kernel(const bf16* __restrict__ Vp, const int* __restrict__ mask,
                  bf16* __restrict__ VpA, bf16* __restrict__ VpB) {
  __shared__ bf16 t[64][80];
  int tix = blockIdx.x, h = blockIdx.y, b = blockIdx.z;
  int j0 = tix * 64, bh = b * HH + h;
  const int* maskb = mask + b * KVN;
  int tid = threadIdx.x;
  int lr = tid >> 3, lc = (tid & 7) * 8;
  for (int p = 0; p < 2; ++p) {
    int j = lr + p * 32;
    int mv = maskb[j0 + j];
    bf16x8 v = *(const bf16x8*)&Vp[(size_t)(b * KVN + j0 + j) * CC + h * HD + lc];
#pragma unroll
    for (int uu = 0; uu < 8; ++uu) t[lc + uu][j] = mv ? v[uu] : (bf16)0.f;
  }
  __syncthreads();
  for (int p = 0; p < 3; ++p) {
    int sp = p * 256 + tid;
    if (sp < 640) {
      int fs = sp >> 6, lane = sp & 63, quad = (sp >> 4) & 3, l15 = sp & 15;
      int ni = fs >> 1, hf = fs & 1;
      bf16x8 v;
      if (ni < 4) {
        v = *(const bf16x8*)&t[ni * 16 + l15][hf * 32 + quad * 8];
      } else {
#pragma unroll
        for (int jj = 0; jj < 8; ++jj)
          v[jj] = (l15 == 0) ? (bf16)(float)maskb[j0 + hf * 32 + quad * 8 + jj]
                             : (bf16)0.f;
      }
      bf16* dst = (fs < 6) ? (VpA + (size_t)fs * (1 << 19))
                           : (VpB + (size_t)(fs - 6) * (1 << 19));
      *(bf16x8*)&dst[((size_t)(bh * 32 + tix)) * 512 + lane * 8] = v;
    }
  }
}

// ---------------- attention v7: round-8 structure (measured 51.4us: grid 512,
// 2qc x 2kh waves, 16 iters, single parallel merge) + base-2 softmax via raw
// v_exp_f32 (1 op; Q pre-scaled by log2e). Round-12 postmortem: the 4-way KV
// split gained no occupancy (VGPR 112 + ~80 AGPR Oacc = ~192 unified regs ->
// still 2 blocks/CU) and libm exp2f is ~6 ops (denormal guards) -> VALUBusy
// 40->53. Revert split; keep only the exp win (2 ops/elem vs 3).
__global__ __launch_bounds__(256, 2)
void attn3(const bf16* __restrict__ Qp, const bf16* __restrict__ Kpack,
           const bf16* __restrict__ VpA, const bf16* __restrict__ VpB,
           bf16* __restrict__ X) {
  __shared__ char smem[49152];      // [0,8K): per-wave P; [8K,48K): merge buffer
  const int tid = threadIdx.x, wave = tid >> 6, lane = tid & 63;
  const int quad = lane >> 4, l15 = lane & 15;
  const int bid = blockIdx.x;
  const int u = bid & 7, s = bid >> 3;
  const int bh = u * 4 + (s & 3), qp = s >> 2;
  const int b = bh >> 4, h = bh & 15;
  const int qc = qp * 2 + (wave >> 1), kh = wave & 1;
  const int q0 = qc * 64;
  const int sw = 2 * (l15 & 7);

  bf16* P = (bf16*)(smem + wave * 2048);
  float* mrg = (float*)(smem + 8192);

  bf16x8 qa[4][2];
#pragma unroll
  for (int g = 0; g < 4; ++g) {
    const bf16* qrow = Qp + ((size_t)(b * NN) + q0 + g * 16 + l15) * CC + h * HD;
    qa[g][0] = *(const bf16x8*)&qrow[quad * 8];
    qa[g][1] = *(const bf16x8*)&qrow[32 + quad * 8];
  }

  f32x4 Oacc[4][5] = {};
  const bf16* kbase = Kpack + (size_t)bh * 32 * 8 * 512;

  for (int it = 0; it < 16; ++it) {
    int t = kh * 16 + it;
    bf16x8 kb[8], vb[10];
#pragma unroll
    for (int fs = 0; fs < 8; ++fs)
      kb[fs] = *(const bf16x8*)&kbase[((size_t)t * 8 + fs) * 512 + lane * 8];
#pragma unroll
    for (int fs = 0; fs < 10; ++fs) {
      const bf16* vbs = (fs < 6) ? (VpA + (size_t)fs * (1 << 19))
                                 : (VpB + (size_t)(fs - 6) * (1 << 19));
      vb[fs] = *(const bf16x8*)&vbs[((size_t)(bh * 32 + t)) * 512 + lane * 8];
    }
#pragma unroll
    for (int g = 0; g < 4; ++g) {
      f32x4 sg[4];
      __builtin_amdgcn_s_setprio(1);
#pragma unroll
      for (int ni = 0; ni < 4; ++ni) {
        f32x4 zz = {};
        zz = __builtin_amdgcn_mfma_f32_16x16x32_bf16(kb[ni * 2], qa[g][0], zz, 0, 0, 0);
        zz = __builtin_amdgcn_mfma_f32_16x16x32_bf16(kb[ni * 2 + 1], qa[g][1], zz, 0, 0, 0);
        sg[ni] = zz;
      }
      __builtin_amdgcn_s_setprio(0);
#pragma unroll
      for (int ni = 0; ni < 4; ++ni) {
        bf16x4 pk;
#pragma unroll
        for (int r = 0; r < 4; ++r) pk[r] = (bf16)exp2_raw(sg[ni][r] - 5.7707802f);
        *(bf16x4*)&P[(l15 * 16 + ((ni * 4 + quad) ^ sw)) * 4] = pk;
      }
      bf16x8 pf0 = *(const bf16x8*)&P[(l15 * 16 + ((quad * 2) ^ sw)) * 4];
      bf16x8 pf1 = *(const bf16x8*)&P[(l15 * 16 + ((8 + quad * 2) ^ sw)) * 4];
      __builtin_amdgcn_s_setprio(1);
#pragma unroll
      for (int ni = 0; ni < 5; ++ni) {
        Oacc[g][ni] = __builtin_amdgcn_mfma_f32_16x16x32_bf16(vb[ni * 2], pf0, Oacc[g][ni], 0, 0, 0);
        Oacc[g][ni] = __builtin_amdgcn_mfma_f32_16x16x32_bf16(vb[ni * 2 + 1], pf1, Oacc[g][ni], 0, 0, 0);
      }
      __builtin_amdgcn_s_setprio(0);
    }
  }
  if (kh == 1) {
    float* dst = mrg + (wave >> 1) * 5120 + lane * 4;
#pragma unroll
    for (int g = 0; g < 4; ++g)
#pragma unroll
      for (int ni = 0; ni < 5; ++ni)
        *(f32x4*)&dst[(g * 5 + ni) * 256] = Oacc[g][ni];
  }
  __syncthreads();
  if (kh == 0) {
    float* src = mrg + (wave >> 1) * 5120 + lane * 4;
#pragma unroll
    for (int g = 0; g < 4; ++g) {
#pragma unroll
      for (int ni = 0; ni < 5; ++ni) {
        f32x4 o = *(const f32x4*)&src[(g * 5 + ni) * 256];
#pragma unroll
        for (int r = 0; r < 4; ++r) Oacc[g][ni][r] += o[r];
      }
      float ls = __shfl(Oacc[g][4][0], l15, 64);
      float rn = 1.0f / ls;
#pragma unroll
      for (int ni = 0; ni < 4; ++ni) {
        bf16x4 ov;
#pragma unroll
        for (int r = 0; r < 4; ++r) ov[r] = (bf16)(Oacc[g][ni][r] * rn);
        *(bf16x4*)&X[((size_t)(b * NN) + q0 + g * 16 + l15) * CC
                     + h * HD + ni * 16 + quad * 4] = ov;
      }
    }
  }
}

// ---------------- projection GEMM: 64x128 tile, BK=64, 8-slot swizzle, grid 512
__global__ __launch_bounds__(256, 4)
void gemm_proj(const bf16* __restrict__ A, const bf16* __restrict__ Bt,
               float* __restrict__ Out) {
  __shared__ bf16 As[64 * 64];    // 8 KB
  __shared__ bf16 Bs[128 * 64];   // 16 KB
  const int bid = blockIdx.x;
  const int u = bid & 7, s = bid >> 3;        // s in [0,64)
  const int m0 = (u * 8 + (s >> 3)) * 64;
  const int n0 = (s & 7) * 128;
  const int tid = threadIdx.x;
  const int wave = tid >> 6, lane = tid & 63;
  const int quad = lane >> 4, l15 = lane & 15;
  const int waveM = (wave >> 1) * 32, waveN = (wave & 1) * 64;
  f32x4 acc[2][4] = {};

  for (int k0 = 0; k0 < CC; k0 += 64) {
#pragma unroll
    for (int p = 0; p < 2; ++p) {
      int ch = p * 256 + tid;
      int r = ch >> 3, c = (ch & 7) ^ (r & 7);
      gload_lds16(A + (size_t)(m0 + r) * CC + k0 + c * 8, &As[ch * 8]);
    }
#pragma unroll
    for (int p = 0; p < 4; ++p) {
      int ch = p * 256 + tid;
      int r = ch >> 3, c = (ch & 7) ^ (r & 7);
      gload_lds16(Bt + (size_t)(n0 + r) * CC + k0 + c * 8, &Bs[ch * 8]);
    }
    __syncthreads();
    bf16x8 af[2][2], bfr[4][2];
#pragma unroll
    for (int i = 0; i < 2; ++i) {
      int rA = waveM + i * 16 + l15;
      af[i][0] = *(const bf16x8*)&As[(rA * 8 + (quad ^ (rA & 7))) * 8];
      af[i][1] = *(const bf16x8*)&As[(rA * 8 + ((quad + 4) ^ (rA & 7))) * 8];
    }
#pragma unroll
    for (int i = 0; i < 4; ++i) {
      int rB = waveN + i * 16 + l15;
      bfr[i][0] = *(const bf16x8*)&Bs[(rB * 8 + (quad ^ (rB & 7))) * 8];
      bfr[i][1] = *(const bf16x8*)&Bs[(rB * 8 + ((quad + 4) ^ (rB & 7))) * 8];
    }
#pragma unroll
    for (int mi = 0; mi < 2; ++mi)
#pragma unroll
      for (int ni = 0; ni < 4; ++ni) {
        acc[mi][ni] = __builtin_amdgcn_mfma_f32_16x16x32_bf16(
            af[mi][0], bfr[ni][0], acc[mi][ni], 0, 0, 0);
        acc[mi][ni] = __builtin_amdgcn_mfma_f32_16x16x32_bf16(
            af[mi][1], bfr[ni][1], acc[mi][ni], 0, 0, 0);
      }
    __syncthreads();
  }
#pragma unroll
  for (int mi = 0; mi < 2; ++mi)
#pragma unroll
    for (int ni = 0; ni < 4; ++ni)
#pragma unroll
      for (int r = 0; r < 4; ++r) {
        int row = m0 + waveM + mi * 16 + quad * 4 + r;
        int col = n0 + waveN + ni * 16 + l15;
        Out[(size_t)row * CC + col] = acc[mi][ni][r];
      }
}

extern "C" void kernel_launch(void* const* d_in, const int* in_sizes, int n_in,
                              void* d_out, int out_size, void* d_ws, size_t ws_size,
                              hipStream_t stream) {
  const float* q    = (const float*)d_in[0];
  const float* k    = (const float*)d_in[1];
  const float* v    = (const float*)d_in[2];
  const int*   mask = (const int*)d_in[3];
  const float* pos  = (const float*)d_in[4];
  const float* qW   = (const float*)d_in[5];
  const float* kW   = (const float*)d_in[6];
  const float* vW   = (const float*)d_in[7];
  const float* pW   = (const float*)d_in[8];
  float* out = (float*)d_out;

  char* w = (char*)d_ws;
  const size_t MB = 1024 * 1024;
  // layout (<=48MB): Wt@0-8; Qp@8-16; Kp@16-24 (dead after kpack -> X aliases);
  // Vp@24-32 (dead after vpack); Abf@32-44 (12MB, dead after gemm_qkv ->
  // Kpack@32-40 and VpB@40-44 overwrite it); VpA@0-6 over dead qWt/kWt/vWt.
  bf16* Wt    = (bf16*)(w);
  bf16* Qp    = (bf16*)(w + 8 * MB);
  bf16* Kp    = (bf16*)(w + 16 * MB);
  bf16* Vp    = (bf16*)(w + 24 * MB);
  bf16* Abf   = (bf16*)(w + 32 * MB);   // 12 MB, live only through gemm_qkv
  bf16* Kpack = (bf16*)(w + 32 * MB);   // 8 MB, written after Abf is dead
  bf16* VpA   = (bf16*)(w);             // 6 MB over dead qWt/kWt/vWt
  bf16* VpB   = (bf16*)(w + 40 * MB);   // 4 MB, written after Abf is dead
  bf16* X     = (bf16*)(w + 16 * MB);   // aliases Kp

  wtrans<<<dim3(16, 16, 4), 256, 0, stream>>>(qW, kW, vW, pW, Wt);
  cvt_qkv<<<dim3(2048, 3), 256, 0, stream>>>(q, k, v, Abf);
  gemm_qkv<<<dim3(768), 256, 0, stream>>>(Abf, Wt, pos, Qp, Kp, Vp);
  kpack_kernel<<<dim3(KVN / 64, HH, BB), 256, 0, stream>>>(Kp, Kpack);
  vpack_kernel<<<dim3(KVN / 64, HH, BB), 256, 0, stream>>>(Vp, mask, VpA, VpB);
  attn3<<<dim3(512), 256, 0, stream>>>(Qp, Kpack, VpA, VpB, X);
  gemm_proj<<<dim3(512), 256, 0, stream>>>(X, Wt + 3 * (size_t)CC * CC, out);
}